// Round 3
// baseline (246.179 us; speedup 1.0000x reference)
//
#include <hip/hip_runtime.h>

// FP8DynamicLinear: x[8192,2048] fp32 -> dynamic per-tensor fp8 quant,
// qweight[2048,2048] (fp8-representable fp32), out = (qx*xs) @ (qw*ws)^T + bias.
static constexpr int M_ = 8192;
static constexpr int K_ = 2048;
static constexpr int N_ = 2048;

#define FP8MAX 448.0f

using f32x4 = __attribute__((ext_vector_type(4))) float;
typedef unsigned int u32;
typedef unsigned char u8;

__device__ __forceinline__ void gload_lds16(const void* g, void* lds) {
  __builtin_amdgcn_global_load_lds((const __attribute__((address_space(1))) void*)g,
                                   (__attribute__((address_space(3))) void*)lds,
                                   16 /*bytes*/, 0 /*offset*/, 0 /*aux*/);
}

// ---------------- pass 1: amax(|x|) ----------------
__global__ void amax_abs_kernel(const float* __restrict__ x, u32* __restrict__ amax_bits, int n4) {
  const float4* x4 = (const float4*)x;
  float m = 0.f;
  int idx = blockIdx.x * blockDim.x + threadIdx.x;
  int stride = gridDim.x * blockDim.x;
  for (int i = idx; i < n4; i += stride) {
    float4 v = x4[i];
    m = fmaxf(m, fmaxf(fmaxf(fabsf(v.x), fabsf(v.y)), fmaxf(fabsf(v.z), fabsf(v.w))));
  }
  #pragma unroll
  for (int off = 32; off > 0; off >>= 1) m = fmaxf(m, __shfl_xor(m, off, 64));
  if ((threadIdx.x & 63) == 0) atomicMax(amax_bits, __float_as_uint(m));  // m>=0: uint order == float order
}

// ---------------- pass 2: quantize x -> fp8 e4m3 (RNE, matches clip+cast) ----------------
__global__ void quant_x_kernel(const float* __restrict__ x, const u32* __restrict__ amax_bits,
                               uint4* __restrict__ qx, int n16) {
  float amax = __uint_as_float(*amax_bits);
  float scale = FP8MAX / fmaxf(amax, 1e-12f);
  int i = blockIdx.x * blockDim.x + threadIdx.x;
  if (i >= n16) return;
  const f32x4* x4 = (const f32x4*)x;
  u32 w[4];
  #pragma unroll
  for (int j = 0; j < 4; ++j) {
    f32x4 v = x4[(size_t)i * 4 + j];
    #pragma unroll
    for (int e = 0; e < 4; ++e) v[e] = fminf(fmaxf(v[e] * scale, -FP8MAX), FP8MAX);
    int p = __builtin_amdgcn_cvt_pk_fp8_f32(v[0], v[1], 0, false);
    p = __builtin_amdgcn_cvt_pk_fp8_f32(v[2], v[3], p, true);
    w[j] = (u32)p;
  }
  qx[i] = make_uint4(w[0], w[1], w[2], w[3]);
}

// ---------------- pass 3: cast qweight (already fp8-representable) -> fp8 bytes ----------------
__global__ void quant_w_kernel(const float* __restrict__ wsrc, uint4* __restrict__ qw, int n16) {
  int i = blockIdx.x * blockDim.x + threadIdx.x;
  if (i >= n16) return;
  const f32x4* w4 = (const f32x4*)wsrc;
  u32 w[4];
  #pragma unroll
  for (int j = 0; j < 4; ++j) {
    f32x4 v = w4[(size_t)i * 4 + j];
    int p = __builtin_amdgcn_cvt_pk_fp8_f32(v[0], v[1], 0, false);
    p = __builtin_amdgcn_cvt_pk_fp8_f32(v[2], v[3], p, true);
    w[j] = (u32)p;
  }
  qw[i] = make_uint4(w[0], w[1], w[2], w[3]);
}

// ---------------- pass 4: fp8 GEMM, C = (qx qw^T) * (xs*ws) + bias ----------------
// 128x128 tile, BK=64 bytes, 4 waves (2x2), 16x16x32 fp8 MFMA.
// LDS tiles [128 rows][64 B] with 16B-chunk XOR swizzle (chunk ^= row&3),
// applied via pre-swizzled GLOBAL source so global_load_lds stays linear (rule 21).
__global__ __launch_bounds__(256, 2) void gemm_fp8_kernel(
    const u8* __restrict__ qx, const u8* __restrict__ qw,
    const u32* __restrict__ amax_bits, const float* __restrict__ wscale_p,
    const float* __restrict__ bias, float* __restrict__ out)
{
  constexpr int BM = 128, BN = 128, BK = 64;
  __shared__ u8 As[BM * BK];
  __shared__ u8 Bs[BN * BK];

  const int tid  = threadIdx.x;
  const int wave = tid >> 6;
  const int lane = tid & 63;
  const int bm = blockIdx.y * BM;
  const int bn = blockIdx.x * BN;

  // ---- staging addressing: thread tid stages 16B chunk `tid` (call 0) and `tid+256` (call 1)
  const int sr = tid >> 2;                 // LDS row 0..63 (call 0), +64 for call 1
  const int sc = tid & 3;                  // 16B chunk-in-row
  const int swzc = (sc ^ (sr & 3)) << 4;   // pre-swizzled global byte offset in row
  const u8* gA0 = qx + (size_t)(bm + sr) * K_ + swzc;
  const u8* gA1 = gA0 + (size_t)64 * K_;
  const u8* gB0 = qw + (size_t)(bn + sr) * K_ + swzc;
  const u8* gB1 = gB0 + (size_t)64 * K_;
  u8* ldsA0 = As + wave * 1024;            // wave-uniform LDS bases
  u8* ldsA1 = As + 4096 + wave * 1024;
  u8* ldsB0 = Bs + wave * 1024;
  u8* ldsB1 = Bs + 4096 + wave * 1024;

  // ---- fragment addressing
  const int wr = wave >> 1, wc = wave & 1;
  const int fr = lane & 15;                // row within 16x16 tile
  const int q  = lane >> 4;                // k-group
  const int swz = (fr & 3) << 4;           // read-side un-swizzle (row&3 == fr&3 here)
  int rowA[4], rowB[4];
  #pragma unroll
  for (int m = 0; m < 4; ++m) rowA[m] = (wr * 64 + m * 16 + fr) * BK;
  #pragma unroll
  for (int n = 0; n < 4; ++n) rowB[n] = (wc * 64 + n * 16 + fr) * BK;

  f32x4 acc[4][4];
  #pragma unroll
  for (int m = 0; m < 4; ++m)
    #pragma unroll
    for (int n = 0; n < 4; ++n)
      acc[m][n] = f32x4{0.f, 0.f, 0.f, 0.f};

  for (int kt = 0; kt < K_ / BK; ++kt) {
    gload_lds16(gA0, ldsA0);
    gload_lds16(gA1, ldsA1);
    gload_lds16(gB0, ldsB0);
    gload_lds16(gB1, ldsB1);
    gA0 += BK; gA1 += BK; gB0 += BK; gB1 += BK;
    __syncthreads();   // compiler drains vmcnt before s_barrier -> LDS tiles ready

    #pragma unroll
    for (int ks = 0; ks < 2; ++ks) {
      const int kb = (ks * 32 + q * 8) ^ swz;
      long a[4], b[4];
      #pragma unroll
      for (int m = 0; m < 4; ++m) a[m] = *(const long*)(As + rowA[m] + kb);
      #pragma unroll
      for (int n = 0; n < 4; ++n) b[n] = *(const long*)(Bs + rowB[n] + kb);
      #pragma unroll
      for (int m = 0; m < 4; ++m)
        #pragma unroll
        for (int n = 0; n < 4; ++n)
          acc[m][n] = __builtin_amdgcn_mfma_f32_16x16x32_fp8_fp8(a[m], b[n], acc[m][n], 0, 0, 0);
    }
    __syncthreads();   // all waves done reading before next stage overwrites
  }

  // ---- epilogue: scale + bias, C/D layout: col=lane&15, row=(lane>>4)*4+reg
  float amax = __uint_as_float(*amax_bits);
  float scale = FP8MAX / fmaxf(amax, 1e-12f);
  float xs = 1.0f / scale;
  float cs = xs * wscale_p[0];
  const int orow = bm + wr * 64;
  const int ocol = bn + wc * 64;
  #pragma unroll
  for (int m = 0; m < 4; ++m) {
    #pragma unroll
    for (int n = 0; n < 4; ++n) {
      const int col = ocol + n * 16 + fr;
      const float bv = bias[col];
      #pragma unroll
      for (int i = 0; i < 4; ++i) {
        const int row = orow + m * 16 + q * 4 + i;
        out[(size_t)row * N_ + col] = acc[m][n][i] * cs + bv;
      }
    }
  }
}

extern "C" void kernel_launch(void* const* d_in, const int* in_sizes, int n_in,
                              void* d_out, int out_size, void* d_ws, size_t ws_size,
                              hipStream_t stream) {
  const float* x       = (const float*)d_in[0];
  const float* qweight = (const float*)d_in[1];
  const float* wscale  = (const float*)d_in[2];
  const float* bias    = (const float*)d_in[3];
  float* out = (float*)d_out;

  u32* amax_bits = (u32*)d_ws;
  u8* qx = (u8*)d_ws + 256;
  u8* qw = qx + (size_t)M_ * K_;

  hipMemsetAsync(d_ws, 0, 256, stream);  // amax slot must start at 0 (ws is poisoned 0xAA)
  amax_abs_kernel<<<1024, 256, 0, stream>>>(x, amax_bits, M_ * K_ / 4);
  quant_x_kernel<<<(M_ * K_ / 16) / 256, 256, 0, stream>>>(x, amax_bits, (uint4*)qx, M_ * K_ / 16);
  quant_w_kernel<<<(N_ * K_ / 16) / 256, 256, 0, stream>>>(qweight, (uint4*)qw, N_ * K_ / 16);
  dim3 grid(N_ / 128, M_ / 128);
  gemm_fp8_kernel<<<grid, 256, 0, stream>>>(qx, qw, amax_bits, wscale, bias, out);
}